// Round 1
// baseline (10049.352 us; speedup 1.0000x reference)
//
#include <hip/hip_runtime.h>
#include <hip/hip_bf16.h>

typedef unsigned int  u32;
typedef unsigned short u16;

#define TT 512
#define BBATCH 32

// ---------- bf16 helpers ----------
__device__ __forceinline__ float bfu2f(u16 u){
  union { u32 i; float f; } v; v.i = ((u32)u) << 16; return v.f;
}
__device__ __forceinline__ float lo_bf(u32 p){
  union { u32 i; float f; } v; v.i = p << 16; return v.f;
}
__device__ __forceinline__ float hi_bf(u32 p){
  union { u32 i; float f; } v; v.i = p & 0xffff0000u; return v.f;
}
__device__ __forceinline__ u16 f2bf_u(float f){
  union { float f; u32 i; } v; v.f = f;
  u32 r = v.i + 0x7fffu + ((v.i >> 16) & 1u);   // RNE
  return (u16)(r >> 16);
}

__device__ __forceinline__ float sigm(float x){
  return 1.f / (1.f + __expf(-x));
}
__device__ __forceinline__ float tanh_fast(float x){
  float e = __expf(-2.f * x);
  return (1.f - e) / (1.f + e);
}

// ---------- weight packing: Whh[4*He, K] fp32 -> [K/2][He] uint4 of bf16 pairs ----------
// dst[k2*He + e] = { pack(Wi[e][2k2],Wi[e][2k2+1]), pack(Wf..), pack(Wg..), pack(Wo..) }
__global__ void pack_whh(const float* __restrict__ W, uint4* __restrict__ dst,
                         int He, int K)
{
  int idx = blockIdx.x * blockDim.x + threadIdx.x;
  int total = (K >> 1) * He;
  if (idx >= total) return;
  int e  = idx % He;
  int k2 = idx / He;
  int k0 = k2 * 2;
  u32 q[4];
#pragma unroll
  for (int g = 0; g < 4; ++g){
    const float* row = W + (size_t)(g * He + e) * K;
    q[g] = (u32)f2bf_u(row[k0]) | ((u32)f2bf_u(row[k0 + 1]) << 16);
  }
  dst[idx] = make_uint4(q[0], q[1], q[2], q[3]);
}

// ---------- fp32 projection GEMM ----------
// C[m,n] = sum_k A_row(m)[k] * W[n,k] + bias[n]
// m = t*32 + b ; A_row(m) = A + tq*a_st + b*a_sb, tq = flip ? 511-t : t
// mode bf16: Cb + m*N + n (ushort). mode f32: Cf + b*c_sb + t*c_st + n.
#define BM 128
#define BN 128
#define BK 32

__global__ __launch_bounds__(256) void proj(
    const float* __restrict__ A, int a_st, int a_sb, int flip, int K,
    const float* __restrict__ W, const float* __restrict__ bias, int N,
    u16* __restrict__ Cb, float* __restrict__ Cf, long c_sb, long c_st)
{
  __shared__ float As[BK][BM + 4];
  __shared__ float Bs[BK][BN + 4];
  const int n0 = blockIdx.x * BN;
  const int m0 = blockIdx.y * BM;
  const int tid = threadIdx.x;
  const int tx = tid & 15, ty = tid >> 4;
  const int lr = tid >> 3;          // 0..31
  const int lc = (tid & 7) * 4;     // 0,4,...,28

  float acc[8][8];
#pragma unroll
  for (int i = 0; i < 8; ++i)
#pragma unroll
    for (int j = 0; j < 8; ++j) acc[i][j] = 0.f;

  const float* arow[4];
#pragma unroll
  for (int rr = 0; rr < 4; ++rr){
    int m = m0 + lr + rr * 32;
    int t = m >> 5, b = m & 31;
    int tq = flip ? (TT - 1 - t) : t;
    arow[rr] = A + (size_t)tq * a_st + (size_t)b * a_sb;
  }

  for (int k0 = 0; k0 < K; k0 += BK){
#pragma unroll
    for (int rr = 0; rr < 4; ++rr){
      float4 v = *(const float4*)(arow[rr] + k0 + lc);
      int m = lr + rr * 32;
      As[lc + 0][m] = v.x; As[lc + 1][m] = v.y;
      As[lc + 2][m] = v.z; As[lc + 3][m] = v.w;
    }
#pragma unroll
    for (int rr = 0; rr < 4; ++rr){
      int n = n0 + lr + rr * 32;
      float4 v = *(const float4*)(W + (size_t)n * K + k0 + lc);
      int nl = lr + rr * 32;
      Bs[lc + 0][nl] = v.x; Bs[lc + 1][nl] = v.y;
      Bs[lc + 2][nl] = v.z; Bs[lc + 3][nl] = v.w;
    }
    __syncthreads();
#pragma unroll
    for (int kk = 0; kk < BK; ++kk){
      float4 a0 = *(const float4*)&As[kk][ty * 8];
      float4 a1 = *(const float4*)&As[kk][ty * 8 + 4];
      float4 b0 = *(const float4*)&Bs[kk][tx * 8];
      float4 b1 = *(const float4*)&Bs[kk][tx * 8 + 4];
      float am[8] = {a0.x,a0.y,a0.z,a0.w,a1.x,a1.y,a1.z,a1.w};
      float bn[8] = {b0.x,b0.y,b0.z,b0.w,b1.x,b1.y,b1.z,b1.w};
#pragma unroll
      for (int i = 0; i < 8; ++i)
#pragma unroll
        for (int j = 0; j < 8; ++j)
          acc[i][j] += am[i] * bn[j];
    }
    __syncthreads();
  }

  float bj[8];
#pragma unroll
  for (int j = 0; j < 8; ++j) bj[j] = bias ? bias[n0 + tx * 8 + j] : 0.f;

  if (Cb){
#pragma unroll
    for (int i = 0; i < 8; ++i){
      int m = m0 + ty * 8 + i;
      ushort4 u0, u1;
      u0.x = f2bf_u(acc[i][0] + bj[0]); u0.y = f2bf_u(acc[i][1] + bj[1]);
      u0.z = f2bf_u(acc[i][2] + bj[2]); u0.w = f2bf_u(acc[i][3] + bj[3]);
      u1.x = f2bf_u(acc[i][4] + bj[4]); u1.y = f2bf_u(acc[i][5] + bj[5]);
      u1.z = f2bf_u(acc[i][6] + bj[6]); u1.w = f2bf_u(acc[i][7] + bj[7]);
      u16* dst = Cb + (size_t)m * N + n0 + tx * 8;
      *(ushort4*)(dst)     = u0;
      *(ushort4*)(dst + 4) = u1;
    }
  } else {
#pragma unroll
    for (int i = 0; i < 8; ++i){
      int m = m0 + ty * 8 + i;
      int t = m >> 5, b = m & 31;
      float* dst = Cf + (size_t)b * c_sb + (size_t)t * c_st + n0 + tx * 8;
      float4 v0 = {acc[i][0] + bj[0], acc[i][1] + bj[1], acc[i][2] + bj[2], acc[i][3] + bj[3]};
      float4 v1 = {acc[i][4] + bj[4], acc[i][5] + bj[5], acc[i][6] + bj[6], acc[i][7] + bj[7]};
      *(float4*)(dst)     = v0;
      *(float4*)(dst + 4) = v1;
    }
  }
}

// ---------- encoder LSTM scan: one block per (dir, batch) ----------
// Wpk: [128][256] uint4 (bf16 k-pairs for gates i,f,g,o), xg: [T][B][1024] bf16
// hout: [T][B][512] fp32, fwd -> cols [0,256), bwd -> cols [256,512) at flipped t
__global__ __launch_bounds__(256) void scan_enc(
    const uint4* __restrict__ WpkF, const uint4* __restrict__ WpkB,
    const u16* __restrict__ xgF, const u16* __restrict__ xgB,
    float* __restrict__ hout)
{
  const int dir = blockIdx.x >> 5, b = blockIdx.x & 31;
  const uint4* __restrict__ Wpk = dir ? WpkB : WpkF;
  const u16*  __restrict__ xg  = dir ? xgB  : xgF;
  const int e = threadIdx.x;               // 0..255 (h element)
  __shared__ u16 hbuf[2][256];
  hbuf[0][e] = 0; hbuf[1][e] = 0;
  float c = 0.f;
  __syncthreads();
  int cur = 0;
  for (int t = 0; t < TT; ++t){
    const u16* xrow = xg + ((size_t)(t * 32 + b)) * 1024 + e;
    float gi = bfu2f(xrow[0]);
    float gf = bfu2f(xrow[256]);
    float gg = bfu2f(xrow[512]);
    float go = bfu2f(xrow[768]);
    const u32* __restrict__ hp = (const u32*)&hbuf[cur][0];
    const uint4* __restrict__ wp = Wpk + e;
#pragma unroll 4
    for (int k2 = 0; k2 < 128; ++k2){
      u32 hpair = hp[k2];
      uint4 q = wp[(size_t)k2 << 8];
      float h0 = lo_bf(hpair), h1 = hi_bf(hpair);
      gi += h0 * lo_bf(q.x); gi += h1 * hi_bf(q.x);
      gf += h0 * lo_bf(q.y); gf += h1 * hi_bf(q.y);
      gg += h0 * lo_bf(q.z); gg += h1 * hi_bf(q.z);
      go += h0 * lo_bf(q.w); go += h1 * hi_bf(q.w);
    }
    float i_ = sigm(gi);
    float f_ = sigm(gf);
    float o_ = sigm(go);
    float g_ = tanh_fast(gg);
    c = f_ * c + i_ * g_;
    float h = o_ * tanh_fast(c);
    int tq = dir ? (TT - 1 - t) : t;
    hout[(((size_t)tq * 32 + b) << 9) + (dir << 8) + e] = h;
    cur ^= 1;
    hbuf[cur][e] = f2bf_u(h);
    __syncthreads();
  }
}

// ---------- decoder LSTM scan: one block per batch, H=128 ----------
__global__ __launch_bounds__(128) void scan_dec(
    const uint4* __restrict__ Wpk, const u16* __restrict__ xg,
    float* __restrict__ y)
{
  const int b = blockIdx.x;
  const int e = threadIdx.x;               // 0..127
  __shared__ u16 hbuf[2][128];
  hbuf[0][e] = 0; hbuf[1][e] = 0;
  float c = 0.f;
  __syncthreads();
  int cur = 0;
  for (int t = 0; t < TT; ++t){
    const u16* xrow = xg + ((size_t)(t * 32 + b)) * 512 + e;
    float gi = bfu2f(xrow[0]);
    float gf = bfu2f(xrow[128]);
    float gg = bfu2f(xrow[256]);
    float go = bfu2f(xrow[384]);
    const u32* __restrict__ hp = (const u32*)&hbuf[cur][0];
    const uint4* __restrict__ wp = Wpk + e;
#pragma unroll 4
    for (int k2 = 0; k2 < 64; ++k2){
      u32 hpair = hp[k2];
      uint4 q = wp[(size_t)k2 << 7];
      float h0 = lo_bf(hpair), h1 = hi_bf(hpair);
      gi += h0 * lo_bf(q.x); gi += h1 * hi_bf(q.x);
      gf += h0 * lo_bf(q.y); gf += h1 * hi_bf(q.y);
      gg += h0 * lo_bf(q.z); gg += h1 * hi_bf(q.z);
      go += h0 * lo_bf(q.w); go += h1 * hi_bf(q.w);
    }
    float i_ = sigm(gi);
    float f_ = sigm(gf);
    float o_ = sigm(go);
    float g_ = tanh_fast(gg);
    c = f_ * c + i_ * g_;
    float h = o_ * tanh_fast(c);
    y[(((size_t)t * 32 + b) << 7) + e] = h;
    cur ^= 1;
    hbuf[cur][e] = f2bf_u(h);
    __syncthreads();
  }
}

extern "C" void kernel_launch(void* const* d_in, const int* in_sizes, int n_in,
                              void* d_out, int out_size, void* d_ws, size_t ws_size,
                              hipStream_t stream)
{
  const float* x        = (const float*)d_in[0];
  const float* e0f_Wih  = (const float*)d_in[1];
  const float* e0f_Whh  = (const float*)d_in[2];
  const float* e0f_b    = (const float*)d_in[3];
  const float* e0b_Wih  = (const float*)d_in[4];
  const float* e0b_Whh  = (const float*)d_in[5];
  const float* e0b_b    = (const float*)d_in[6];
  const float* e1f_Wih  = (const float*)d_in[7];
  const float* e1f_Whh  = (const float*)d_in[8];
  const float* e1f_b    = (const float*)d_in[9];
  const float* e1b_Wih  = (const float*)d_in[10];
  const float* e1b_Whh  = (const float*)d_in[11];
  const float* e1b_b    = (const float*)d_in[12];
  const float* dec_Wih  = (const float*)d_in[13];
  const float* dec_Whh  = (const float*)d_in[14];
  const float* dec_b    = (const float*)d_in[15];
  const float* out_W    = (const float*)d_in[16];
  const float* out_b    = (const float*)d_in[17];

  char* p = (char*)d_ws;
  auto alloc = [&](size_t bytes){
    void* r = (void*)p;
    p += (bytes + 255) & ~(size_t)255;
    return r;
  };
  const size_t M = (size_t)TT * BBATCH;         // 16384
  u16*  xgA = (u16*)  alloc(M * 1024 * 2);      // 33.5 MB
  u16*  xgB = (u16*)  alloc(M * 1024 * 2);      // 33.5 MB
  float* h0 = (float*)alloc(M * 512 * 4);       // 33.5 MB
  float* h1 = (float*)alloc(M * 512 * 4);       // 33.5 MB
  float* yb = (float*)alloc(M * 128 * 4);       //  8.4 MB
  uint4* wE0f = (uint4*)alloc(128 * 256 * 16);
  uint4* wE0b = (uint4*)alloc(128 * 256 * 16);
  uint4* wE1f = (uint4*)alloc(128 * 256 * 16);
  uint4* wE1b = (uint4*)alloc(128 * 256 * 16);
  uint4* wDec = (uint4*)alloc(64 * 128 * 16);

  // pack recurrent weights to bf16 pairs
  pack_whh<<<128, 256, 0, stream>>>(e0f_Whh, wE0f, 256, 256);
  pack_whh<<<128, 256, 0, stream>>>(e0b_Whh, wE0b, 256, 256);
  pack_whh<<<128, 256, 0, stream>>>(e1f_Whh, wE1f, 256, 256);
  pack_whh<<<128, 256, 0, stream>>>(e1b_Whh, wE1b, 256, 256);
  pack_whh<<<32,  256, 0, stream>>>(dec_Whh, wDec, 128, 128);

  // encoder layer 0: x [B,T,128] -> xg (a_st=128 per t, a_sb=T*128 per b)
  proj<<<dim3(8, 128), 256, 0, stream>>>(x, 128, TT * 128, 0, 128,
      e0f_Wih, e0f_b, 1024, xgA, nullptr, 0, 0);
  proj<<<dim3(8, 128), 256, 0, stream>>>(x, 128, TT * 128, 1, 128,
      e0b_Wih, e0b_b, 1024, xgB, nullptr, 0, 0);
  scan_enc<<<64, 256, 0, stream>>>(wE0f, wE0b, xgA, xgB, h0);

  // encoder layer 1: h0 [T,B,512]
  proj<<<dim3(8, 128), 256, 0, stream>>>(h0, BBATCH * 512, 512, 0, 512,
      e1f_Wih, e1f_b, 1024, xgA, nullptr, 0, 0);
  proj<<<dim3(8, 128), 256, 0, stream>>>(h0, BBATCH * 512, 512, 1, 512,
      e1b_Wih, e1b_b, 1024, xgB, nullptr, 0, 0);
  scan_enc<<<64, 256, 0, stream>>>(wE1f, wE1b, xgA, xgB, h1);

  // decoder: h1 [T,B,512] -> xg [m][512]
  proj<<<dim3(4, 128), 256, 0, stream>>>(h1, BBATCH * 512, 512, 0, 512,
      dec_Wih, dec_b, 512, xgA, nullptr, 0, 0);
  scan_dec<<<32, 128, 0, stream>>>(wDec, xgA, yb);

  // output linear: y [T,B,128] -> d_out [B,T,128] fp32
  proj<<<dim3(1, 128), 256, 0, stream>>>(yb, BBATCH * 128, 128, 0, 128,
      out_W, out_b, 128, nullptr, (float*)d_out, (long)TT * 128, 128);
}

// Round 2
// 8000.038 us; speedup vs baseline: 1.2562x; 1.2562x over previous
//
#include <hip/hip_runtime.h>
#include <hip/hip_bf16.h>

typedef unsigned int  u32;
typedef unsigned short u16;
typedef float f32x16 __attribute__((ext_vector_type(16)));
typedef short bf16x8 __attribute__((ext_vector_type(8)));

#define TT 512
#define BBATCH 32

// ---------- bf16 helpers ----------
__device__ __forceinline__ float bfu2f(u16 u){
  union { u32 i; float f; } v; v.i = ((u32)u) << 16; return v.f;
}
__device__ __forceinline__ u16 f2bf_u(float f){
  union { float f; u32 i; } v; v.f = f;
  u32 r = v.i + 0x7fffu + ((v.i >> 16) & 1u);   // RNE
  return (u16)(r >> 16);
}
__device__ __forceinline__ float sigm(float x){
  return 1.f / (1.f + __expf(-x));
}
__device__ __forceinline__ float tanh_s(float x){
  float ax = fabsf(x);
  float e = __expf(-2.f * ax);
  float t = (1.f - e) / (1.f + e);
  return copysignf(t, x);
}

// ---------- fp32 -> bf16 weight convert ----------
__global__ void tobf16(const float* __restrict__ src, u16* __restrict__ dst, int n)
{
  int i = blockIdx.x * blockDim.x + threadIdx.x;
  if (i < n) dst[i] = f2bf_u(src[i]);
}

__global__ void zflags(u32* flags)
{
  if (threadIdx.x < 16) flags[threadIdx.x] = 0;
}

// ---------- projection GEMM (A fp32 or bf16 per abf) ----------
#define BM 128
#define BN 128
#define BK 32

__global__ __launch_bounds__(256) void proj(
    const void* __restrict__ A, int abf, long a_st, long a_sb, int flip, int K,
    const float* __restrict__ W, const float* __restrict__ bias, int N,
    u16* __restrict__ Cb, float* __restrict__ Cf, long c_sb, long c_st)
{
  __shared__ float As[BK][BM + 4];
  __shared__ float Bs[BK][BN + 4];
  const int n0 = blockIdx.x * BN;
  const int m0 = blockIdx.y * BM;
  const int tid = threadIdx.x;
  const int tx = tid & 15, ty = tid >> 4;
  const int lr = tid >> 3;          // 0..31
  const int lc = (tid & 7) * 4;     // 0,4,...,28

  float acc[8][8];
#pragma unroll
  for (int i = 0; i < 8; ++i)
#pragma unroll
    for (int j = 0; j < 8; ++j) acc[i][j] = 0.f;

  const char* arowb[4];
  const int esz = abf ? 2 : 4;
#pragma unroll
  for (int rr = 0; rr < 4; ++rr){
    int m = m0 + lr + rr * 32;
    int t = m >> 5, b = m & 31;
    int tq = flip ? (TT - 1 - t) : t;
    arowb[rr] = (const char*)A + ((size_t)tq * a_st + (size_t)b * a_sb) * esz;
  }

  for (int k0 = 0; k0 < K; k0 += BK){
#pragma unroll
    for (int rr = 0; rr < 4; ++rr){
      int m = lr + rr * 32;
      if (abf){
        ushort4 v = *(const ushort4*)((const u16*)arowb[rr] + k0 + lc);
        As[lc + 0][m] = bfu2f(v.x); As[lc + 1][m] = bfu2f(v.y);
        As[lc + 2][m] = bfu2f(v.z); As[lc + 3][m] = bfu2f(v.w);
      } else {
        float4 v = *(const float4*)((const float*)arowb[rr] + k0 + lc);
        As[lc + 0][m] = v.x; As[lc + 1][m] = v.y;
        As[lc + 2][m] = v.z; As[lc + 3][m] = v.w;
      }
    }
#pragma unroll
    for (int rr = 0; rr < 4; ++rr){
      int n = n0 + lr + rr * 32;
      float4 v = *(const float4*)(W + (size_t)n * K + k0 + lc);
      int nl = lr + rr * 32;
      Bs[lc + 0][nl] = v.x; Bs[lc + 1][nl] = v.y;
      Bs[lc + 2][nl] = v.z; Bs[lc + 3][nl] = v.w;
    }
    __syncthreads();
#pragma unroll
    for (int kk = 0; kk < BK; ++kk){
      float4 a0 = *(const float4*)&As[kk][ty * 8];
      float4 a1 = *(const float4*)&As[kk][ty * 8 + 4];
      float4 b0 = *(const float4*)&Bs[kk][tx * 8];
      float4 b1 = *(const float4*)&Bs[kk][tx * 8 + 4];
      float am[8] = {a0.x,a0.y,a0.z,a0.w,a1.x,a1.y,a1.z,a1.w};
      float bn[8] = {b0.x,b0.y,b0.z,b0.w,b1.x,b1.y,b1.z,b1.w};
#pragma unroll
      for (int i = 0; i < 8; ++i)
#pragma unroll
        for (int j = 0; j < 8; ++j)
          acc[i][j] += am[i] * bn[j];
    }
    __syncthreads();
  }

  float bj[8];
#pragma unroll
  for (int j = 0; j < 8; ++j) bj[j] = bias ? bias[n0 + tx * 8 + j] : 0.f;

  if (Cb){
#pragma unroll
    for (int i = 0; i < 8; ++i){
      int m = m0 + ty * 8 + i;
      ushort4 u0, u1;
      u0.x = f2bf_u(acc[i][0] + bj[0]); u0.y = f2bf_u(acc[i][1] + bj[1]);
      u0.z = f2bf_u(acc[i][2] + bj[2]); u0.w = f2bf_u(acc[i][3] + bj[3]);
      u1.x = f2bf_u(acc[i][4] + bj[4]); u1.y = f2bf_u(acc[i][5] + bj[5]);
      u1.z = f2bf_u(acc[i][6] + bj[6]); u1.w = f2bf_u(acc[i][7] + bj[7]);
      u16* dst = Cb + (size_t)m * N + n0 + tx * 8;
      *(ushort4*)(dst)     = u0;
      *(ushort4*)(dst + 4) = u1;
    }
  } else {
#pragma unroll
    for (int i = 0; i < 8; ++i){
      int m = m0 + ty * 8 + i;
      int t = m >> 5, b = m & 31;
      float* dst = Cf + (size_t)b * c_sb + (size_t)t * c_st + n0 + tx * 8;
      float4 v0 = {acc[i][0] + bj[0], acc[i][1] + bj[1], acc[i][2] + bj[2], acc[i][3] + bj[3]};
      float4 v1 = {acc[i][4] + bj[4], acc[i][5] + bj[5], acc[i][6] + bj[6], acc[i][7] + bj[7]};
      *(float4*)(dst)     = v0;
      *(float4*)(dst + 4) = v1;
    }
  }
}

// ---------- encoder scan: weights VGPR-stationary, MFMA, 4-block h exchange ----------
// grid 8 blocks: dir = bx>>2, quarter q = bx&3. Block owns e in [64q,64q+64), all 4 gates.
// Wd packed bf16 [1024][256] (row = g*256 + e). xg bf16 [T*32+b][1024].
// exch: bf16 h (as u32 pairs) [row][512], row = (dir? flip t : t)*32 + b, col = dir*256 + e.
__global__ __launch_bounds__(512, 1) void scan_enc2(
    const u16* __restrict__ WF, const u16* __restrict__ WB,
    const u16* __restrict__ xgF, const u16* __restrict__ xgB,
    u32* __restrict__ exch, u32* __restrict__ flags)
{
  const int bx = blockIdx.x;
  const int dir = bx >> 2, q = bx & 3;
  const u16* __restrict__ Wd = dir ? WB : WF;
  const u16* __restrict__ xg = dir ? xgB : xgF;
  const int tid = threadIdx.x;
  const int l = tid & 63, w = tid >> 6;

  __shared__ u16 hA[32 * 256];     // h[b][k] swizzled, 16 KB
  __shared__ float gex[32 * 256];  // gate pre-acts [b][n], 32 KB

  { // zero hA
    u32* p = (u32*)hA;
#pragma unroll
    for (int i = 0; i < 8; ++i) p[tid + i * 512] = 0;
  }

  // persistent B fragments: wave w owns n-tile w (rows nl = w*32 + lane&31)
  const int nl = w * 32 + (l & 31);
  const int grow = (nl >> 6) * 256 + q * 64 + (nl & 63);
  const int kbase = (l >> 5) << 3;
  bf16x8 bfr[16];
#pragma unroll
  for (int ks = 0; ks < 16; ++ks)
    bfr[ks] = *reinterpret_cast<const bf16x8*>(Wd + (size_t)grow * 256 + ks * 16 + kbase);

  char* hAb = (char*)hA;
  const int m_l = l & 31;
  const int abase = m_l * 512 + ((l >> 5) << 4);
  const int aswz = (m_l & 15) << 4;

  const int b = tid >> 4;
  const int e4 = (tid & 15) << 2;
  float cr[4];
#pragma unroll
  for (int i = 0; i < 4; ++i) cr[i] = 0.f;

  const int remq = (tid < 3) ? (tid + (tid >= q ? 1 : 0)) : 0;

  __syncthreads();

  for (int t = 0; t < TT; ++t){
    f32x16 acc;
#pragma unroll
    for (int i = 0; i < 16; ++i) acc[i] = 0.f;

    if (t > 0){
#pragma unroll
      for (int ks = 0; ks < 16; ++ks){
        bf16x8 a = *reinterpret_cast<const bf16x8*>(hAb + ((abase + ks * 32) ^ aswz));
        acc = __builtin_amdgcn_mfma_f32_32x32x16_bf16(a, bfr[ks], acc, 0, 0, 0);
      }
    }
    { // scatter acc to gex[m][nl]
      const int mb = 4 * (l >> 5);
#pragma unroll
      for (int r = 0; r < 16; ++r){
        int m = (r & 3) + 8 * (r >> 2) + mb;
        gex[m * 256 + nl] = acc[r];
      }
    }
    __syncthreads();

    { // pointwise: 4 cells (b, e4+cc)
      const u16* xr = xg + ((size_t)(t * 32 + b)) * 1024 + q * 64 + e4;
      float4 gi4 = *(const float4*)&gex[b * 256 +   0 + e4];
      float4 gf4 = *(const float4*)&gex[b * 256 +  64 + e4];
      float4 gg4 = *(const float4*)&gex[b * 256 + 128 + e4];
      float4 go4 = *(const float4*)&gex[b * 256 + 192 + e4];
      ushort4 xi = *(const ushort4*)(xr + 0);
      ushort4 xf = *(const ushort4*)(xr + 256);
      ushort4 xgv= *(const ushort4*)(xr + 512);
      ushort4 xo = *(const ushort4*)(xr + 768);
      float giv[4] = {gi4.x, gi4.y, gi4.z, gi4.w};
      float gfv[4] = {gf4.x, gf4.y, gf4.z, gf4.w};
      float ggv[4] = {gg4.x, gg4.y, gg4.z, gg4.w};
      float gov[4] = {go4.x, go4.y, go4.z, go4.w};
      u16 xiv[4] = {xi.x, xi.y, xi.z, xi.w};
      u16 xfv[4] = {xf.x, xf.y, xf.z, xf.w};
      u16 xgvv[4]= {xgv.x, xgv.y, xgv.z, xgv.w};
      u16 xov[4] = {xo.x, xo.y, xo.z, xo.w};
      float h_[4];
#pragma unroll
      for (int cc = 0; cc < 4; ++cc){
        float i_ = sigm(giv[cc] + bfu2f(xiv[cc]));
        float f_ = sigm(gfv[cc] + bfu2f(xfv[cc]));
        float g_ = tanh_s(ggv[cc] + bfu2f(xgvv[cc]));
        float o_ = sigm(gov[cc] + bfu2f(xov[cc]));
        cr[cc] = f_ * cr[cc] + i_ * g_;
        h_[cc] = o_ * tanh_s(cr[cc]);
      }
      int row = (dir ? (TT - 1 - t) : t) * 32 + b;
      int col = dir * 256 + q * 64 + e4;
      u32 h01 = (u32)f2bf_u(h_[0]) | ((u32)f2bf_u(h_[1]) << 16);
      u32 h23 = (u32)f2bf_u(h_[2]) | ((u32)f2bf_u(h_[3]) << 16);
      __hip_atomic_store(exch + (size_t)row * 256 + (col >> 1),     h01,
                         __ATOMIC_RELAXED, __HIP_MEMORY_SCOPE_AGENT);
      __hip_atomic_store(exch + (size_t)row * 256 + (col >> 1) + 1, h23,
                         __ATOMIC_RELAXED, __HIP_MEMORY_SCOPE_AGENT);
      // own slice into hA (swizzled)
      int kcol = q * 64 + e4;
      u32 byte = (u32)(b * 512 + kcol * 2) ^ (u32)((b & 15) << 4);
      *(uint2*)(hAb + byte) = make_uint2(h01, h23);
    }

    if (t == TT - 1) break;

    __syncthreads();   // drains global stores (vmcnt before barrier) + hA own visible
    if (tid == 0)
      __hip_atomic_store(flags + dir * 4 + q, (u32)(t + 1),
                         __ATOMIC_RELEASE, __HIP_MEMORY_SCOPE_AGENT);
    if (tid < 3){
      while (__hip_atomic_load(flags + dir * 4 + remq,
                               __ATOMIC_ACQUIRE, __HIP_MEMORY_SCOPE_AGENT) < (u32)(t + 1)) {}
    }
    __syncthreads();

    { // stage 3 remote quarters (3*1024 dwords) into hA
      int rowbase = (dir ? (TT - 1 - t) : t) * 32;
#pragma unroll
      for (int it = 0; it < 6; ++it){
        int j = tid + it * 512;
        int rqi = j >> 10;
        int rq = rqi + (rqi >= q ? 1 : 0);
        int rem = j & 1023;
        int b2 = rem >> 5;
        int dw = rem & 31;
        u32 v = __hip_atomic_load(exch + (size_t)(rowbase + b2) * 256 + dir * 128 + rq * 32 + dw,
                                  __ATOMIC_RELAXED, __HIP_MEMORY_SCOPE_AGENT);
        u32 byte = (u32)(b2 * 512 + rq * 128 + dw * 4) ^ (u32)((b2 & 15) << 4);
        *(u32*)(hAb + byte) = v;
      }
    }
    __syncthreads();
  }
}

// ---------- decoder scan: single block, weights VGPR-stationary, no sync ----------
// Wd bf16 [512][128] (row = g*128 + e). xg bf16 [m][512]. yb f32 [m][128].
__global__ __launch_bounds__(512, 1) void scan_dec2(
    const u16* __restrict__ Wd, const u16* __restrict__ xg, float* __restrict__ yb)
{
  const int tid = threadIdx.x;
  const int l = tid & 63, w = tid >> 6;

  __shared__ u16 hA[32 * 128];     // 8 KB
  __shared__ float gex[32 * 512];  // 64 KB

  { u32* p = (u32*)hA;
#pragma unroll
    for (int i = 0; i < 4; ++i) p[tid + i * 512] = 0;
  }

  const int kbase = (l >> 5) << 3;
  const int nl0 = w * 64 + (l & 31);
  const int nl1 = nl0 + 32;
  bf16x8 bf0[8], bf1[8];
#pragma unroll
  for (int ks = 0; ks < 8; ++ks){
    bf0[ks] = *reinterpret_cast<const bf16x8*>(Wd + (size_t)nl0 * 128 + ks * 16 + kbase);
    bf1[ks] = *reinterpret_cast<const bf16x8*>(Wd + (size_t)nl1 * 128 + ks * 16 + kbase);
  }

  char* hAb = (char*)hA;
  const int m_l = l & 31;
  const int abase = m_l * 256 + ((l >> 5) << 4);
  const int aswz = (m_l & 15) << 4;

  const int b = tid >> 4;
  const int e8 = (tid & 15) << 3;
  float cr[8];
#pragma unroll
  for (int i = 0; i < 8; ++i) cr[i] = 0.f;

  __syncthreads();

  for (int t = 0; t < TT; ++t){
    f32x16 a0, a1;
#pragma unroll
    for (int i = 0; i < 16; ++i){ a0[i] = 0.f; a1[i] = 0.f; }

    if (t > 0){
#pragma unroll
      for (int ks = 0; ks < 8; ++ks){
        bf16x8 a = *reinterpret_cast<const bf16x8*>(hAb + ((abase + ks * 32) ^ aswz));
        a0 = __builtin_amdgcn_mfma_f32_32x32x16_bf16(a, bf0[ks], a0, 0, 0, 0);
        a1 = __builtin_amdgcn_mfma_f32_32x32x16_bf16(a, bf1[ks], a1, 0, 0, 0);
      }
    }
    {
      const int mb = 4 * (l >> 5);
#pragma unroll
      for (int r = 0; r < 16; ++r){
        int m = (r & 3) + 8 * (r >> 2) + mb;
        gex[m * 512 + nl0] = a0[r];
        gex[m * 512 + nl1] = a1[r];
      }
    }
    __syncthreads();

    { // pointwise: 8 cells (b, e8+j)
      const u16* xr = xg + ((size_t)(t * 32 + b)) * 512 + e8;
      float h_[8];
#pragma unroll
      for (int half = 0; half < 2; ++half){
        float4 gi4 = *(const float4*)&gex[b * 512 +   0 + e8 + half * 4];
        float4 gf4 = *(const float4*)&gex[b * 512 + 128 + e8 + half * 4];
        float4 gg4 = *(const float4*)&gex[b * 512 + 256 + e8 + half * 4];
        float4 go4 = *(const float4*)&gex[b * 512 + 384 + e8 + half * 4];
        ushort4 xi = *(const ushort4*)(xr +   0 + half * 4);
        ushort4 xf = *(const ushort4*)(xr + 128 + half * 4);
        ushort4 xgv= *(const ushort4*)(xr + 256 + half * 4);
        ushort4 xo = *(const ushort4*)(xr + 384 + half * 4);
        float giv[4] = {gi4.x, gi4.y, gi4.z, gi4.w};
        float gfv[4] = {gf4.x, gf4.y, gf4.z, gf4.w};
        float ggv[4] = {gg4.x, gg4.y, gg4.z, gg4.w};
        float gov[4] = {go4.x, go4.y, go4.z, go4.w};
        u16 xiv[4] = {xi.x, xi.y, xi.z, xi.w};
        u16 xfv[4] = {xf.x, xf.y, xf.z, xf.w};
        u16 xgvv[4]= {xgv.x, xgv.y, xgv.z, xgv.w};
        u16 xov[4] = {xo.x, xo.y, xo.z, xo.w};
#pragma unroll
        for (int j = 0; j < 4; ++j){
          int cc = half * 4 + j;
          float i_ = sigm(giv[j] + bfu2f(xiv[j]));
          float f_ = sigm(gfv[j] + bfu2f(xfv[j]));
          float g_ = tanh_s(ggv[j] + bfu2f(xgvv[j]));
          float o_ = sigm(gov[j] + bfu2f(xov[j]));
          cr[cc] = f_ * cr[cc] + i_ * g_;
          h_[cc] = o_ * tanh_s(cr[cc]);
        }
      }
      // yb f32
      float* yd = yb + ((size_t)(t * 32 + b)) * 128 + e8;
      float4 y0 = {h_[0], h_[1], h_[2], h_[3]};
      float4 y1 = {h_[4], h_[5], h_[6], h_[7]};
      *(float4*)(yd)     = y0;
      *(float4*)(yd + 4) = y1;
      // hA (swizzled), 8 bf16 = 16 B
      u32 h01 = (u32)f2bf_u(h_[0]) | ((u32)f2bf_u(h_[1]) << 16);
      u32 h23 = (u32)f2bf_u(h_[2]) | ((u32)f2bf_u(h_[3]) << 16);
      u32 h45 = (u32)f2bf_u(h_[4]) | ((u32)f2bf_u(h_[5]) << 16);
      u32 h67 = (u32)f2bf_u(h_[6]) | ((u32)f2bf_u(h_[7]) << 16);
      u32 byte = (u32)(b * 256 + e8 * 2) ^ (u32)((b & 15) << 4);
      *(uint4*)(hAb + byte) = make_uint4(h01, h23, h45, h67);
    }
    __syncthreads();
  }
}

extern "C" void kernel_launch(void* const* d_in, const int* in_sizes, int n_in,
                              void* d_out, int out_size, void* d_ws, size_t ws_size,
                              hipStream_t stream)
{
  const float* x        = (const float*)d_in[0];
  const float* e0f_Wih  = (const float*)d_in[1];
  const float* e0f_Whh  = (const float*)d_in[2];
  const float* e0f_b    = (const float*)d_in[3];
  const float* e0b_Wih  = (const float*)d_in[4];
  const float* e0b_Whh  = (const float*)d_in[5];
  const float* e0b_b    = (const float*)d_in[6];
  const float* e1f_Wih  = (const float*)d_in[7];
  const float* e1f_Whh  = (const float*)d_in[8];
  const float* e1f_b    = (const float*)d_in[9];
  const float* e1b_Wih  = (const float*)d_in[10];
  const float* e1b_Whh  = (const float*)d_in[11];
  const float* e1b_b    = (const float*)d_in[12];
  const float* dec_Wih  = (const float*)d_in[13];
  const float* dec_Whh  = (const float*)d_in[14];
  const float* dec_b    = (const float*)d_in[15];
  const float* out_W    = (const float*)d_in[16];
  const float* out_b    = (const float*)d_in[17];

  char* p = (char*)d_ws;
  auto alloc = [&](size_t bytes){
    void* r = (void*)p;
    p += (bytes + 255) & ~(size_t)255;
    return r;
  };
  const size_t M = (size_t)TT * BBATCH;          // 16384
  u16* xgA  = (u16*)alloc(M * 1024 * 2);         // 33.6 MB
  u16* xgB  = (u16*)alloc(M * 1024 * 2);         // 33.6 MB
  u32* exch = (u32*)alloc(M * 512 * 2);          // 16.8 MB (bf16 h, dword view)
  float* yb = (float*)alloc(M * 128 * 4);        //  8.4 MB
  u16* wE0f = (u16*)alloc(1024 * 256 * 2);
  u16* wE0b = (u16*)alloc(1024 * 256 * 2);
  u16* wE1f = (u16*)alloc(1024 * 256 * 2);
  u16* wE1b = (u16*)alloc(1024 * 256 * 2);
  u16* wDec = (u16*)alloc(512 * 128 * 2);
  u32* flags = (u32*)alloc(256);

  zflags<<<1, 64, 0, stream>>>(flags);
  tobf16<<<1024, 256, 0, stream>>>(e0f_Whh, wE0f, 1024 * 256);
  tobf16<<<1024, 256, 0, stream>>>(e0b_Whh, wE0b, 1024 * 256);
  tobf16<<<1024, 256, 0, stream>>>(e1f_Whh, wE1f, 1024 * 256);
  tobf16<<<1024, 256, 0, stream>>>(e1b_Whh, wE1b, 1024 * 256);
  tobf16<<<256,  256, 0, stream>>>(dec_Whh, wDec, 512 * 128);

  // encoder layer 0 projections: x [B,T,128] f32
  proj<<<dim3(8, 128), 256, 0, stream>>>(x, 0, 128, (long)TT * 128, 0, 128,
      e0f_Wih, e0f_b, 1024, xgA, nullptr, 0, 0);
  proj<<<dim3(8, 128), 256, 0, stream>>>(x, 0, 128, (long)TT * 128, 1, 128,
      e0b_Wih, e0b_b, 1024, xgB, nullptr, 0, 0);
  scan_enc2<<<8, 512, 0, stream>>>(wE0f, wE0b, xgA, xgB, exch, flags);

  // encoder layer 1 projections: A = exch bf16 [t*32+b][512]
  proj<<<dim3(8, 128), 256, 0, stream>>>(exch, 1, (long)BBATCH * 512, 512, 0, 512,
      e1f_Wih, e1f_b, 1024, xgA, nullptr, 0, 0);
  proj<<<dim3(8, 128), 256, 0, stream>>>(exch, 1, (long)BBATCH * 512, 512, 1, 512,
      e1b_Wih, e1b_b, 1024, xgB, nullptr, 0, 0);
  scan_enc2<<<8, 512, 0, stream>>>(wE1f, wE1b, xgA, xgB, exch, flags + 8);

  // decoder projection: A = exch (layer-1 h) bf16, N=512 -> xgA
  proj<<<dim3(4, 128), 256, 0, stream>>>(exch, 1, (long)BBATCH * 512, 512, 0, 512,
      dec_Wih, dec_b, 512, xgA, nullptr, 0, 0);
  scan_dec2<<<1, 512, 0, stream>>>(wDec, xgA, yb);

  // output linear: yb f32 [t*32+b][128] -> d_out [B,T,128] f32
  proj<<<dim3(1, 128), 256, 0, stream>>>(yb, 0, (long)BBATCH * 128, 128, 0, 128,
      out_W, out_b, 128, nullptr, (float*)d_out, (long)TT * 128, 128);
}

// Round 3
// 6136.124 us; speedup vs baseline: 1.6377x; 1.3038x over previous
//
#include <hip/hip_runtime.h>
#include <hip/hip_bf16.h>

typedef unsigned int  u32;
typedef unsigned short u16;
typedef unsigned long long u64;
typedef float f32x16 __attribute__((ext_vector_type(16)));
typedef short bf16x8 __attribute__((ext_vector_type(8)));

#define TT 512
#define BBATCH 32

// ---------- helpers ----------
__device__ __forceinline__ float bfu2f(u16 u){
  union { u32 i; float f; } v; v.i = ((u32)u) << 16; return v.f;
}
__device__ __forceinline__ u16 f2bf_u(float f){
  union { float f; u32 i; } v; v.f = f;
  u32 r = v.i + 0x7fffu + ((v.i >> 16) & 1u);   // RNE
  return (u16)(r >> 16);
}
__device__ __forceinline__ float rcp_fast(float x){
  float r; asm("v_rcp_f32 %0, %1" : "=v"(r) : "v"(x)); return r;
}
__device__ __forceinline__ float sigm(float x){
  return rcp_fast(1.f + __expf(-x));
}
__device__ __forceinline__ float tanh_s(float x){
  float ax = fabsf(x);
  float e = __expf(-2.f * ax);
  float t = (1.f - e) * rcp_fast(1.f + e);
  return copysignf(t, x);
}
__device__ __forceinline__ float q4(ushort4 v, int cc){
  return bfu2f(cc == 0 ? v.x : cc == 1 ? v.y : cc == 2 ? v.z : v.w);
}

// ---------- fp32 -> bf16 weight convert ----------
__global__ void tobf16(const float* __restrict__ src, u16* __restrict__ dst, int n)
{
  int i = blockIdx.x * blockDim.x + threadIdx.x;
  if (i < n) dst[i] = f2bf_u(src[i]);
}

__global__ void zflags(u32* flags)
{
  if (threadIdx.x < 16) flags[threadIdx.x] = 0;
}

// ---------- projection GEMM (A fp32 or bf16 per abf) ----------
#define BM 128
#define BN 128
#define BK 32

__global__ __launch_bounds__(256) void proj(
    const void* __restrict__ A, int abf, long a_st, long a_sb, int flip, int K,
    const float* __restrict__ W, const float* __restrict__ bias, int N,
    u16* __restrict__ Cb, float* __restrict__ Cf, long c_sb, long c_st)
{
  __shared__ float As[BK][BM + 4];
  __shared__ float Bs[BK][BN + 4];
  const int n0 = blockIdx.x * BN;
  const int m0 = blockIdx.y * BM;
  const int tid = threadIdx.x;
  const int tx = tid & 15, ty = tid >> 4;
  const int lr = tid >> 3;          // 0..31
  const int lc = (tid & 7) * 4;     // 0,4,...,28

  float acc[8][8];
#pragma unroll
  for (int i = 0; i < 8; ++i)
#pragma unroll
    for (int j = 0; j < 8; ++j) acc[i][j] = 0.f;

  const char* arowb[4];
  const int esz = abf ? 2 : 4;
#pragma unroll
  for (int rr = 0; rr < 4; ++rr){
    int m = m0 + lr + rr * 32;
    int t = m >> 5, b = m & 31;
    int tq = flip ? (TT - 1 - t) : t;
    arowb[rr] = (const char*)A + ((size_t)tq * a_st + (size_t)b * a_sb) * esz;
  }

  for (int k0 = 0; k0 < K; k0 += BK){
#pragma unroll
    for (int rr = 0; rr < 4; ++rr){
      int m = lr + rr * 32;
      if (abf){
        ushort4 v = *(const ushort4*)((const u16*)arowb[rr] + k0 + lc);
        As[lc + 0][m] = bfu2f(v.x); As[lc + 1][m] = bfu2f(v.y);
        As[lc + 2][m] = bfu2f(v.z); As[lc + 3][m] = bfu2f(v.w);
      } else {
        float4 v = *(const float4*)((const float*)arowb[rr] + k0 + lc);
        As[lc + 0][m] = v.x; As[lc + 1][m] = v.y;
        As[lc + 2][m] = v.z; As[lc + 3][m] = v.w;
      }
    }
#pragma unroll
    for (int rr = 0; rr < 4; ++rr){
      int n = n0 + lr + rr * 32;
      float4 v = *(const float4*)(W + (size_t)n * K + k0 + lc);
      int nl = lr + rr * 32;
      Bs[lc + 0][nl] = v.x; Bs[lc + 1][nl] = v.y;
      Bs[lc + 2][nl] = v.z; Bs[lc + 3][nl] = v.w;
    }
    __syncthreads();
#pragma unroll
    for (int kk = 0; kk < BK; ++kk){
      float4 a0 = *(const float4*)&As[kk][ty * 8];
      float4 a1 = *(const float4*)&As[kk][ty * 8 + 4];
      float4 b0 = *(const float4*)&Bs[kk][tx * 8];
      float4 b1 = *(const float4*)&Bs[kk][tx * 8 + 4];
      float am[8] = {a0.x,a0.y,a0.z,a0.w,a1.x,a1.y,a1.z,a1.w};
      float bn[8] = {b0.x,b0.y,b0.z,b0.w,b1.x,b1.y,b1.z,b1.w};
#pragma unroll
      for (int i = 0; i < 8; ++i)
#pragma unroll
        for (int j = 0; j < 8; ++j)
          acc[i][j] += am[i] * bn[j];
    }
    __syncthreads();
  }

  float bj[8];
#pragma unroll
  for (int j = 0; j < 8; ++j) bj[j] = bias ? bias[n0 + tx * 8 + j] : 0.f;

  if (Cb){
#pragma unroll
    for (int i = 0; i < 8; ++i){
      int m = m0 + ty * 8 + i;
      ushort4 u0, u1;
      u0.x = f2bf_u(acc[i][0] + bj[0]); u0.y = f2bf_u(acc[i][1] + bj[1]);
      u0.z = f2bf_u(acc[i][2] + bj[2]); u0.w = f2bf_u(acc[i][3] + bj[3]);
      u1.x = f2bf_u(acc[i][4] + bj[4]); u1.y = f2bf_u(acc[i][5] + bj[5]);
      u1.z = f2bf_u(acc[i][6] + bj[6]); u1.w = f2bf_u(acc[i][7] + bj[7]);
      u16* dst = Cb + (size_t)m * N + n0 + tx * 8;
      *(ushort4*)(dst)     = u0;
      *(ushort4*)(dst + 4) = u1;
    }
  } else {
#pragma unroll
    for (int i = 0; i < 8; ++i){
      int m = m0 + ty * 8 + i;
      int t = m >> 5, b = m & 31;
      float* dst = Cf + (size_t)b * c_sb + (size_t)t * c_st + n0 + tx * 8;
      float4 v0 = {acc[i][0] + bj[0], acc[i][1] + bj[1], acc[i][2] + bj[2], acc[i][3] + bj[3]};
      float4 v1 = {acc[i][4] + bj[4], acc[i][5] + bj[5], acc[i][6] + bj[6], acc[i][7] + bj[7]};
      *(float4*)(dst)     = v0;
      *(float4*)(dst + 4) = v1;
    }
  }
}

// ---------- encoder scan ----------
// Real blocks at bx = q*8 + dir (dir<2, q<4): 4 quarter-blocks of a direction
// share XCD `dir` under bx%8 round-robin placement. Others exit.
// Wd bf16 [1024][256] (row = g*256 + e). xg bf16 [T*32+b][1024].
// exch bf16 h [row][512] (dword view), row = (dir? flip t : t)*32 + b, col = dir*256 + e.
#define GEXS 257
__global__ __launch_bounds__(512, 1) void scan_enc2(
    const u16* __restrict__ WF, const u16* __restrict__ WB,
    const u16* __restrict__ xgF, const u16* __restrict__ xgB,
    u32* __restrict__ exch, u32* __restrict__ flags)
{
  const int bx = blockIdx.x;
  const int dir = bx & 7;
  if (dir >= 2) return;
  const int q = bx >> 3;
  const u16* __restrict__ Wd = dir ? WB : WF;
  const u16* __restrict__ xg = dir ? xgB : xgF;
  const int tid = threadIdx.x;
  const int l = tid & 63, w = tid >> 6;

  __shared__ u16 hA[32 * 256];        // h[b][k] swizzled, 16 KB
  __shared__ float gex[32 * GEXS];    // gate pre-acts [b][n], padded

  { u32* p = (u32*)hA;
#pragma unroll
    for (int i = 0; i < 8; ++i) p[tid + i * 512] = 0;
  }

  // persistent B fragments: wave w owns n-tile w (rows nl = w*32 + lane&31)
  const int nl = w * 32 + (l & 31);
  const int grow = (nl >> 6) * 256 + q * 64 + (nl & 63);
  const int kbase = (l >> 5) << 3;
  bf16x8 bfr[16];
#pragma unroll
  for (int ks = 0; ks < 16; ++ks)
    bfr[ks] = *reinterpret_cast<const bf16x8*>(Wd + (size_t)grow * 256 + ks * 16 + kbase);

  char* hAb = (char*)hA;
  const int m_l = l & 31;
  const int abase = m_l * 512 + ((l >> 5) << 4);
  const int aswz = (m_l & 15) << 4;

  const int b = tid >> 4;
  const int e4 = (tid & 15) << 2;
  float cr[4];
#pragma unroll
  for (int i = 0; i < 4; ++i) cr[i] = 0.f;

  const int remq = (tid < 3) ? (tid + (tid >= q ? 1 : 0)) : 0;

  // prefetch xg(t=0)
  const u16* xb0 = xg + (size_t)b * 1024 + q * 64 + e4;
  ushort4 pxi = *(const ushort4*)(xb0 + 0);
  ushort4 pxf = *(const ushort4*)(xb0 + 256);
  ushort4 pxg = *(const ushort4*)(xb0 + 512);
  ushort4 pxo = *(const ushort4*)(xb0 + 768);

  __syncthreads();

  for (int t = 0; t < TT; ++t){
    f32x16 acc0, acc1;
#pragma unroll
    for (int i = 0; i < 16; ++i){ acc0[i] = 0.f; acc1[i] = 0.f; }

    if (t > 0){
#pragma unroll
      for (int ks = 0; ks < 16; ks += 2){
        bf16x8 aA = *reinterpret_cast<const bf16x8*>(hAb + ((abase + ks * 32) ^ aswz));
        bf16x8 aB = *reinterpret_cast<const bf16x8*>(hAb + ((abase + ks * 32 + 32) ^ aswz));
        acc0 = __builtin_amdgcn_mfma_f32_32x32x16_bf16(aA, bfr[ks],     acc0, 0, 0, 0);
        acc1 = __builtin_amdgcn_mfma_f32_32x32x16_bf16(aB, bfr[ks + 1], acc1, 0, 0, 0);
      }
    }
    { // scatter acc to gex[m][nl] (stride GEXS: banks (m+nl)%32, conflict-free)
      const int mb = 4 * (l >> 5);
#pragma unroll
      for (int r = 0; r < 16; ++r){
        int m = (r & 3) + 8 * (r >> 2) + mb;
        gex[m * GEXS + nl] = acc0[r] + acc1[r];
      }
    }
    __syncthreads();

    { // pointwise: 4 cells (b, e4+cc); gates from gex (scalar reads) + prefetched xg
      const float* gxr = &gex[b * GEXS];
      float h_[4];
#pragma unroll
      for (int cc = 0; cc < 4; ++cc){
        float i_ = sigm(gxr[  0 + e4 + cc] + q4(pxi, cc));
        float f_ = sigm(gxr[ 64 + e4 + cc] + q4(pxf, cc));
        float g_ = tanh_s(gxr[128 + e4 + cc] + q4(pxg, cc));
        float o_ = sigm(gxr[192 + e4 + cc] + q4(pxo, cc));
        cr[cc] = f_ * cr[cc] + i_ * g_;
        h_[cc] = o_ * tanh_s(cr[cc]);
      }
      int row = (dir ? (TT - 1 - t) : t) * 32 + b;
      int col = dir * 256 + q * 64 + e4;
      u32 h01 = (u32)f2bf_u(h_[0]) | ((u32)f2bf_u(h_[1]) << 16);
      u32 h23 = (u32)f2bf_u(h_[2]) | ((u32)f2bf_u(h_[3]) << 16);
      u64 hq = ((u64)h23 << 32) | (u64)h01;
      __hip_atomic_store((u64*)exch + (size_t)row * 128 + (col >> 2), hq,
                         __ATOMIC_RELAXED, __HIP_MEMORY_SCOPE_AGENT);
      // own slice into hA (swizzled)
      u32 byte = (u32)(b * 512 + (q * 64 + e4) * 2) ^ (u32)((b & 15) << 4);
      *(uint2*)(hAb + byte) = make_uint2(h01, h23);
    }

    // prefetch xg(t+1) — latency absorbed at the barriers below
    {
      int tn = (t + 1 < TT) ? t + 1 : t;
      const u16* xn = xg + ((size_t)(tn * 32 + b)) * 1024 + q * 64 + e4;
      pxi = *(const ushort4*)(xn + 0);
      pxf = *(const ushort4*)(xn + 256);
      pxg = *(const ushort4*)(xn + 512);
      pxo = *(const ushort4*)(xn + 768);
    }

    if (t == TT - 1) break;

    __syncthreads();   // drains exch stores + prefetch
    if (tid == 0)
      __hip_atomic_store(flags + dir * 4 + q, (u32)(t + 1),
                         __ATOMIC_RELEASE, __HIP_MEMORY_SCOPE_AGENT);
    if (tid < 3){
      while (__hip_atomic_load(flags + dir * 4 + remq,
                               __ATOMIC_ACQUIRE, __HIP_MEMORY_SCOPE_AGENT) < (u32)(t + 1)) {}
    }
    __syncthreads();

    { // stage 3 remote quarters (1536 u64) into hA
      int rowbase = (dir ? (TT - 1 - t) : t) * 32;
      const u64* exch64 = (const u64*)exch;
#pragma unroll
      for (int it = 0; it < 3; ++it){
        int j = tid + it * 512;
        int rqi = j >> 9;
        int rq = rqi + (rqi >= q ? 1 : 0);
        int rem = j & 511;
        int b2 = rem >> 4;
        int u8i = rem & 15;
        u64 v = __hip_atomic_load(exch64 + (size_t)(rowbase + b2) * 128 + dir * 64 + rq * 16 + u8i,
                                  __ATOMIC_RELAXED, __HIP_MEMORY_SCOPE_AGENT);
        u32 byte = (u32)(b2 * 512 + rq * 128 + u8i * 8) ^ (u32)((b2 & 15) << 4);
        *(u64*)(hAb + byte) = v;
      }
    }
    __syncthreads();
  }
}

// ---------- decoder scan: single block, weights VGPR-stationary ----------
// Wd bf16 [512][128] (row = g*128 + e). xg bf16 [m][512]. yb f32 [m][128].
#define GDXS 513
__global__ __launch_bounds__(512, 1) void scan_dec2(
    const u16* __restrict__ Wd, const u16* __restrict__ xg, float* __restrict__ yb)
{
  const int tid = threadIdx.x;
  const int l = tid & 63, w = tid >> 6;

  __shared__ u16 hA[32 * 128];        // 8 KB
  __shared__ float gex[32 * GDXS];    // ~64 KB

  { u32* p = (u32*)hA;
#pragma unroll
    for (int i = 0; i < 4; ++i) p[tid + i * 512] = 0;
  }

  const int kbase = (l >> 5) << 3;
  const int nl0 = w * 64 + (l & 31);
  const int nl1 = nl0 + 32;
  bf16x8 bf0[8], bf1[8];
#pragma unroll
  for (int ks = 0; ks < 8; ++ks){
    bf0[ks] = *reinterpret_cast<const bf16x8*>(Wd + (size_t)nl0 * 128 + ks * 16 + kbase);
    bf1[ks] = *reinterpret_cast<const bf16x8*>(Wd + (size_t)nl1 * 128 + ks * 16 + kbase);
  }

  char* hAb = (char*)hA;
  const int m_l = l & 31;
  const int abase = m_l * 256 + ((l >> 5) << 4);
  const int aswz = (m_l & 15) << 4;

  const int b = tid >> 4;
  const int e8 = (tid & 15) << 3;
  float cr[8];
#pragma unroll
  for (int i = 0; i < 8; ++i) cr[i] = 0.f;

  // prefetch xg(t=0)
  const u16* xb0 = xg + (size_t)b * 512 + e8;
  ushort4 pxi0 = *(const ushort4*)(xb0 +   0), pxi1 = *(const ushort4*)(xb0 +   4);
  ushort4 pxf0 = *(const ushort4*)(xb0 + 128), pxf1 = *(const ushort4*)(xb0 + 132);
  ushort4 pxg0 = *(const ushort4*)(xb0 + 256), pxg1 = *(const ushort4*)(xb0 + 260);
  ushort4 pxo0 = *(const ushort4*)(xb0 + 384), pxo1 = *(const ushort4*)(xb0 + 388);

  __syncthreads();

  for (int t = 0; t < TT; ++t){
    f32x16 a0e, a0o, a1e, a1o;
#pragma unroll
    for (int i = 0; i < 16; ++i){ a0e[i] = 0.f; a0o[i] = 0.f; a1e[i] = 0.f; a1o[i] = 0.f; }

    if (t > 0){
#pragma unroll
      for (int ks = 0; ks < 8; ks += 2){
        bf16x8 aA = *reinterpret_cast<const bf16x8*>(hAb + ((abase + ks * 32) ^ aswz));
        bf16x8 aB = *reinterpret_cast<const bf16x8*>(hAb + ((abase + ks * 32 + 32) ^ aswz));
        a0e = __builtin_amdgcn_mfma_f32_32x32x16_bf16(aA, bf0[ks],     a0e, 0, 0, 0);
        a1e = __builtin_amdgcn_mfma_f32_32x32x16_bf16(aA, bf1[ks],     a1e, 0, 0, 0);
        a0o = __builtin_amdgcn_mfma_f32_32x32x16_bf16(aB, bf0[ks + 1], a0o, 0, 0, 0);
        a1o = __builtin_amdgcn_mfma_f32_32x32x16_bf16(aB, bf1[ks + 1], a1o, 0, 0, 0);
      }
    }
    {
      const int mb = 4 * (l >> 5);
#pragma unroll
      for (int r = 0; r < 16; ++r){
        int m = (r & 3) + 8 * (r >> 2) + mb;
        gex[m * GDXS + nl0] = a0e[r] + a0o[r];
        gex[m * GDXS + nl1] = a1e[r] + a1o[r];
      }
    }
    __syncthreads();

    { // pointwise: 8 cells
      const float* gxr = &gex[b * GDXS];
      float h_[8];
#pragma unroll
      for (int cc = 0; cc < 8; ++cc){
        float xi = (cc < 4) ? q4(pxi0, cc) : q4(pxi1, cc - 4);
        float xf = (cc < 4) ? q4(pxf0, cc) : q4(pxf1, cc - 4);
        float xgv= (cc < 4) ? q4(pxg0, cc) : q4(pxg1, cc - 4);
        float xo = (cc < 4) ? q4(pxo0, cc) : q4(pxo1, cc - 4);
        float i_ = sigm(gxr[  0 + e8 + cc] + xi);
        float f_ = sigm(gxr[128 + e8 + cc] + xf);
        float g_ = tanh_s(gxr[256 + e8 + cc] + xgv);
        float o_ = sigm(gxr[384 + e8 + cc] + xo);
        cr[cc] = f_ * cr[cc] + i_ * g_;
        h_[cc] = o_ * tanh_s(cr[cc]);
      }
      float* yd = yb + ((size_t)(t * 32 + b)) * 128 + e8;
      float4 y0 = {h_[0], h_[1], h_[2], h_[3]};
      float4 y1 = {h_[4], h_[5], h_[6], h_[7]};
      *(float4*)(yd)     = y0;
      *(float4*)(yd + 4) = y1;
      u32 h01 = (u32)f2bf_u(h_[0]) | ((u32)f2bf_u(h_[1]) << 16);
      u32 h23 = (u32)f2bf_u(h_[2]) | ((u32)f2bf_u(h_[3]) << 16);
      u32 h45 = (u32)f2bf_u(h_[4]) | ((u32)f2bf_u(h_[5]) << 16);
      u32 h67 = (u32)f2bf_u(h_[6]) | ((u32)f2bf_u(h_[7]) << 16);
      u32 byte = (u32)(b * 256 + e8 * 2) ^ (u32)((b & 15) << 4);
      *(uint4*)(hAb + byte) = make_uint4(h01, h23, h45, h67);
    }

    { // prefetch xg(t+1)
      int tn = (t + 1 < TT) ? t + 1 : t;
      const u16* xn = xg + ((size_t)(tn * 32 + b)) * 512 + e8;
      pxi0 = *(const ushort4*)(xn +   0); pxi1 = *(const ushort4*)(xn +   4);
      pxf0 = *(const ushort4*)(xn + 128); pxf1 = *(const ushort4*)(xn + 132);
      pxg0 = *(const ushort4*)(xn + 256); pxg1 = *(const ushort4*)(xn + 260);
      pxo0 = *(const ushort4*)(xn + 384); pxo1 = *(const ushort4*)(xn + 388);
    }
    __syncthreads();
  }
}

extern "C" void kernel_launch(void* const* d_in, const int* in_sizes, int n_in,
                              void* d_out, int out_size, void* d_ws, size_t ws_size,
                              hipStream_t stream)
{
  const float* x        = (const float*)d_in[0];
  const float* e0f_Wih  = (const float*)d_in[1];
  const float* e0f_Whh  = (const float*)d_in[2];
  const float* e0f_b    = (const float*)d_in[3];
  const float* e0b_Wih  = (const float*)d_in[4];
  const float* e0b_Whh  = (const float*)d_in[5];
  const float* e0b_b    = (const float*)d_in[6];
  const float* e1f_Wih  = (const float*)d_in[7];
  const float* e1f_Whh  = (const float*)d_in[8];
  const float* e1f_b    = (const float*)d_in[9];
  const float* e1b_Wih  = (const float*)d_in[10];
  const float* e1b_Whh  = (const float*)d_in[11];
  const float* e1b_b    = (const float*)d_in[12];
  const float* dec_Wih  = (const float*)d_in[13];
  const float* dec_Whh  = (const float*)d_in[14];
  const float* dec_b    = (const float*)d_in[15];
  const float* out_W    = (const float*)d_in[16];
  const float* out_b    = (const float*)d_in[17];

  char* p = (char*)d_ws;
  auto alloc = [&](size_t bytes){
    void* r = (void*)p;
    p += (bytes + 255) & ~(size_t)255;
    return r;
  };
  const size_t M = (size_t)TT * BBATCH;          // 16384
  u16* xgA  = (u16*)alloc(M * 1024 * 2);
  u16* xgB  = (u16*)alloc(M * 1024 * 2);
  u32* exch = (u32*)alloc(M * 512 * 2);
  float* yb = (float*)alloc(M * 128 * 4);
  u16* wE0f = (u16*)alloc(1024 * 256 * 2);
  u16* wE0b = (u16*)alloc(1024 * 256 * 2);
  u16* wE1f = (u16*)alloc(1024 * 256 * 2);
  u16* wE1b = (u16*)alloc(1024 * 256 * 2);
  u16* wDec = (u16*)alloc(512 * 128 * 2);
  u32* flags = (u32*)alloc(256);

  zflags<<<1, 64, 0, stream>>>(flags);
  tobf16<<<1024, 256, 0, stream>>>(e0f_Whh, wE0f, 1024 * 256);
  tobf16<<<1024, 256, 0, stream>>>(e0b_Whh, wE0b, 1024 * 256);
  tobf16<<<1024, 256, 0, stream>>>(e1f_Whh, wE1f, 1024 * 256);
  tobf16<<<1024, 256, 0, stream>>>(e1b_Whh, wE1b, 1024 * 256);
  tobf16<<<256,  256, 0, stream>>>(dec_Whh, wDec, 512 * 128);

  // encoder layer 0 projections: x [B,T,128] f32
  proj<<<dim3(8, 128), 256, 0, stream>>>(x, 0, 128, (long)TT * 128, 0, 128,
      e0f_Wih, e0f_b, 1024, xgA, nullptr, 0, 0);
  proj<<<dim3(8, 128), 256, 0, stream>>>(x, 0, 128, (long)TT * 128, 1, 128,
      e0b_Wih, e0b_b, 1024, xgB, nullptr, 0, 0);
  scan_enc2<<<32, 512, 0, stream>>>(wE0f, wE0b, xgA, xgB, exch, flags);

  // encoder layer 1 projections: A = exch bf16 [t*32+b][512]
  proj<<<dim3(8, 128), 256, 0, stream>>>(exch, 1, (long)BBATCH * 512, 512, 0, 512,
      e1f_Wih, e1f_b, 1024, xgA, nullptr, 0, 0);
  proj<<<dim3(8, 128), 256, 0, stream>>>(exch, 1, (long)BBATCH * 512, 512, 1, 512,
      e1b_Wih, e1b_b, 1024, xgB, nullptr, 0, 0);
  scan_enc2<<<32, 512, 0, stream>>>(wE1f, wE1b, xgA, xgB, exch, flags + 8);

  // decoder projection: A = exch (layer-1 h) bf16, N=512 -> xgA
  proj<<<dim3(4, 128), 256, 0, stream>>>(exch, 1, (long)BBATCH * 512, 512, 0, 512,
      dec_Wih, dec_b, 512, xgA, nullptr, 0, 0);
  scan_dec2<<<1, 512, 0, stream>>>(wDec, xgA, yb);

  // output linear: yb f32 [t*32+b][128] -> d_out [B,T,128] f32
  proj<<<dim3(1, 128), 256, 0, stream>>>(yb, 0, (long)BBATCH * 128, 128, 0, 128,
      out_W, out_b, 128, nullptr, (float*)d_out, (long)TT * 128, 128);
}